// Round 1
// baseline (84.508 us; speedup 1.0000x reference)
//
#include <hip/hip_runtime.h>
#include <math.h>

// Problem constants (B=1): m [S,R,C], msa_mask [S,R], out [S,R,C]
#define S_SEQ 512
#define R_RES 64
#define C_CH  8
#define H_HD  8

// One block per residue column i. 512 threads, one per sequence position s.
// CH=1 collapses attention to a scalar context per (i,h):
//   ctx[h] = sum_k softmax_k(q[h]*k[k]) * v[k]   over valid k
//   out[s,c] = sum_h mask[s]*gate[s,h]*ctx[h]*wo[c,h] + bo[c]
__global__ __launch_bounds__(512) void msa_col_global_attn(
    const float* __restrict__ m,       // [S,R,C]
    const float* __restrict__ mask_g,  // [S,R]
    const float* __restrict__ ln_w,    // [C]
    const float* __restrict__ ln_b,    // [C]
    const float* __restrict__ wq,      // [H,C]
    const float* __restrict__ wk,      // [1,C]
    const float* __restrict__ wv,      // [1,C]
    const float* __restrict__ wg,      // [H,C]
    const float* __restrict__ bg,      // [H]
    const float* __restrict__ wo,      // [C,H]
    const float* __restrict__ bo,      // [C]
    float* __restrict__ out)           // [S,R,C]
{
    const int i    = blockIdx.x;       // residue column
    const int s    = threadIdx.x;      // sequence position
    const int wave = s >> 6;
    const int lane = s & 63;

    __shared__ float sred[8][17];      // 8 waves x up-to-16 partials (+pad)

    // ---- load m[s,i,0..7] (contiguous, 32B aligned) ----
    const float* mp = m + (s * R_RES + i) * C_CH;
    float4 a0 = *(const float4*)(mp);
    float4 a1 = *(const float4*)(mp + 4);
    float x[8] = {a0.x, a0.y, a0.z, a0.w, a1.x, a1.y, a1.z, a1.w};
    const float msk   = mask_g[s * R_RES + i];
    const bool  valid = (msk > 0.f);

    // ---- layernorm over channels ----
    float mu = 0.f;
    #pragma unroll
    for (int c = 0; c < 8; ++c) mu += x[c];
    mu *= 0.125f;
    float var = 0.f;
    #pragma unroll
    for (int c = 0; c < 8; ++c) { float d = x[c] - mu; var += d * d; }
    var *= 0.125f;
    const float rinv = rsqrtf(var + 1e-5f);
    float n[8];
    #pragma unroll
    for (int c = 0; c < 8; ++c) n[c] = (x[c] - mu) * rinv * ln_w[c] + ln_b[c];

    // ---- k,v projections (CH=1) ----
    float kv = 0.f, vv = 0.f;
    #pragma unroll
    for (int c = 0; c < 8; ++c) { kv += n[c] * wk[c]; vv += n[c] * wv[c]; }

    // ---- stage-1 block reduction: masked channel sums, count, kmax/kmin ----
    float r[11];
    #pragma unroll
    for (int c = 0; c < 8; ++c) r[c] = n[c] * msk;
    r[8]  = msk;
    r[9]  = valid ? kv : -INFINITY;    // running max over valid s
    r[10] = valid ? kv :  INFINITY;    // running min over valid s
    #pragma unroll
    for (int d = 1; d < 64; d <<= 1) {
        #pragma unroll
        for (int j = 0; j < 9; ++j) r[j] += __shfl_xor(r[j], d, 64);
        r[9]  = fmaxf(r[9],  __shfl_xor(r[9],  d, 64));
        r[10] = fminf(r[10], __shfl_xor(r[10], d, 64));
    }
    if (lane == 0) {
        #pragma unroll
        for (int j = 0; j < 11; ++j) sred[wave][j] = r[j];
    }
    __syncthreads();

    float qg[8] = {0,0,0,0,0,0,0,0};
    float cnt = 0.f, kmax = -INFINITY, kmin = INFINITY;
    #pragma unroll
    for (int w = 0; w < 8; ++w) {
        #pragma unroll
        for (int c = 0; c < 8; ++c) qg[c] += sred[w][c];
        cnt  += sred[w][8];
        kmax = fmaxf(kmax, sred[w][9]);
        kmin = fminf(kmin, sred[w][10]);
    }
    const float rdenom = 1.f / (cnt + 1e-5f);
    float qgn[8];
    #pragma unroll
    for (int c = 0; c < 8; ++c) qgn[c] = qg[c] * rdenom;

    // ---- per-head global query ----
    float qh[8];
    #pragma unroll
    for (int h = 0; h < 8; ++h) {
        float acc = 0.f;
        #pragma unroll
        for (int c = 0; c < 8; ++c) acc += qgn[c] * wq[h * 8 + c];
        qh[h] = acc;
    }

    // ---- stage-2 reduction: per-h softmax denominator + weighted v ----
    float r2[16];
    #pragma unroll
    for (int h = 0; h < 8; ++h) {
        const float rowmax = (qh[h] >= 0.f) ? qh[h] * kmax : qh[h] * kmin;
        const float e = valid ? __expf(qh[h] * kv - rowmax) : 0.f;
        r2[h]     = e;
        r2[8 + h] = e * vv;
    }
    #pragma unroll
    for (int d = 1; d < 64; d <<= 1) {
        #pragma unroll
        for (int j = 0; j < 16; ++j) r2[j] += __shfl_xor(r2[j], d, 64);
    }
    __syncthreads();                    // everyone done reading stage-1 sred
    if (lane == 0) {
        #pragma unroll
        for (int j = 0; j < 16; ++j) sred[wave][j] = r2[j];
    }
    __syncthreads();

    float ctx[8];
    #pragma unroll
    for (int h = 0; h < 8; ++h) {
        float Z = 0.f, Cs = 0.f;
        #pragma unroll
        for (int w = 0; w < 8; ++w) { Z += sred[w][h]; Cs += sred[w][8 + h]; }
        ctx[h] = (Z > 0.f) ? (Cs / Z) : 0.f;
    }

    // ---- gate, output projection ----
    float o8[8];
    #pragma unroll
    for (int c = 0; c < 8; ++c) o8[c] = bo[c];
    if (valid) {
        #pragma unroll
        for (int h = 0; h < 8; ++h) {
            float g = bg[h];
            #pragma unroll
            for (int c = 0; c < 8; ++c) g += n[c] * wg[h * 8 + c];
            const float gate = 1.f / (1.f + __expf(-g));
            const float oh = gate * ctx[h];
            #pragma unroll
            for (int c = 0; c < 8; ++c) o8[c] += oh * wo[c * 8 + h];
        }
    }
    float* op = out + (s * R_RES + i) * C_CH;
    *(float4*)(op)     = make_float4(o8[0], o8[1], o8[2], o8[3]);
    *(float4*)(op + 4) = make_float4(o8[4], o8[5], o8[6], o8[7]);
}

extern "C" void kernel_launch(void* const* d_in, const int* in_sizes, int n_in,
                              void* d_out, int out_size, void* d_ws, size_t ws_size,
                              hipStream_t stream) {
    const float* m     = (const float*)d_in[0];
    const float* mmask = (const float*)d_in[1];
    const float* ln_w  = (const float*)d_in[2];
    const float* ln_b  = (const float*)d_in[3];
    const float* wq    = (const float*)d_in[4];
    const float* wk    = (const float*)d_in[5];
    const float* wv    = (const float*)d_in[6];
    const float* wg    = (const float*)d_in[7];
    const float* bg    = (const float*)d_in[8];
    const float* wo    = (const float*)d_in[9];
    const float* bo    = (const float*)d_in[10];
    float* out = (float*)d_out;

    msa_col_global_attn<<<dim3(R_RES), dim3(S_SEQ), 0, stream>>>(
        m, mmask, ln_w, ln_b, wq, wk, wv, wg, bg, wo, bo, out);
}

// Round 2
// 79.316 us; speedup vs baseline: 1.0655x; 1.0655x over previous
//
#include <hip/hip_runtime.h>
#include <math.h>

// Problem constants (B=1): m [S,R,C], msa_mask [S,R], out [S,R,C]
#define S_SEQ 512
#define R_RES 64
#define C_CH  8
#define H_HD  8

// One block per residue column i, 512 threads (8 waves), one thread per s.
// CH=1 collapses attention to a scalar context per (i,h):
//   ctx[h] = sum_k softmax_k(q[h]*k[k]) * v[k]   over valid k
//   out[s,c] = sum_h mask[s]*sigmoid(g[s,h])*ctx[h]*wo[c,h] + bo[c]
// Stage-2 is head-per-wave: wave h reduces head h over all 512 s via LDS.
__global__ __launch_bounds__(512) void msa_col_global_attn(
    const float* __restrict__ m,       // [S,R,C]
    const float* __restrict__ mask_g,  // [S,R]
    const float* __restrict__ ln_w,    // [C]
    const float* __restrict__ ln_b,    // [C]
    const float* __restrict__ wq,      // [H,C]
    const float* __restrict__ wk,      // [1,C]
    const float* __restrict__ wv,      // [1,C]
    const float* __restrict__ wg,      // [H,C]
    const float* __restrict__ bg,      // [H]
    const float* __restrict__ wo,      // [C,H]
    const float* __restrict__ bo,      // [C]
    float* __restrict__ out)           // [S,R,C]
{
    const int i    = blockIdx.x;
    const int s    = threadIdx.x;
    const int wave = s >> 6;
    const int lane = s & 63;

    __shared__ __align__(16) float kvs[S_SEQ];
    __shared__ __align__(16) float vvs[S_SEQ];
    __shared__ __align__(16) float mks[S_SEQ];
    __shared__ __align__(16) float part[8][12];  // 11 used; 12 for float4 rows
    __shared__ __align__(16) float ctxs[8];

    // ---- load m[s,i,0..7] (32B contiguous) + mask ----
    const float* mp = m + (s * R_RES + i) * C_CH;
    float4 a0 = *(const float4*)(mp);
    float4 a1 = *(const float4*)(mp + 4);
    float x[8] = {a0.x, a0.y, a0.z, a0.w, a1.x, a1.y, a1.z, a1.w};
    const float msk   = mask_g[s * R_RES + i];
    const bool  valid = (msk > 0.f);

    // ---- layernorm over channels ----
    float mu = 0.f;
    #pragma unroll
    for (int c = 0; c < 8; ++c) mu += x[c];
    mu *= 0.125f;
    float var = 0.f;
    #pragma unroll
    for (int c = 0; c < 8; ++c) { float d = x[c] - mu; var += d * d; }
    var *= 0.125f;
    const float rinv = rsqrtf(var + 1e-5f);
    float n[8];
    #pragma unroll
    for (int c = 0; c < 8; ++c) n[c] = (x[c] - mu) * rinv * ln_w[c] + ln_b[c];

    // ---- k,v projections (CH=1) ----
    float kv = 0.f, vv = 0.f;
    #pragma unroll
    for (int c = 0; c < 8; ++c) { kv += n[c] * wk[c]; vv += n[c] * wv[c]; }

    // ---- gate pre-activation (independent of the reduction chain) ----
    float gh[8];
    #pragma unroll
    for (int h = 0; h < 8; ++h) {
        float g = bg[h];
        #pragma unroll
        for (int c = 0; c < 8; ++c) g += n[c] * wg[h * 8 + c];
        gh[h] = g;
    }

    // ---- publish per-s scalars for stage-2 ----
    kvs[s] = kv;
    vvs[s] = vv;
    mks[s] = msk;

    // ---- stage-1: masked channel sums, count, kmax/kmin over valid s ----
    float r[11];
    #pragma unroll
    for (int c = 0; c < 8; ++c) r[c] = n[c] * msk;
    r[8]  = msk;
    r[9]  = valid ? kv : -INFINITY;
    r[10] = valid ? kv :  INFINITY;
    #pragma unroll
    for (int d = 1; d < 64; d <<= 1) {
        #pragma unroll
        for (int j = 0; j < 9; ++j) r[j] += __shfl_xor(r[j], d, 64);
        r[9]  = fmaxf(r[9],  __shfl_xor(r[9],  d, 64));
        r[10] = fminf(r[10], __shfl_xor(r[10], d, 64));
    }
    if (lane == 0) {
        #pragma unroll
        for (int j = 0; j < 11; ++j) part[wave][j] = r[j];
    }
    __syncthreads();   // barrier 1: part[], kvs/vvs/mks all visible

    // ---- combine wave partials (vectorized broadcast reads) ----
    float qg[8] = {0,0,0,0,0,0,0,0};
    float cnt = 0.f, kmax = -INFINITY, kmin = INFINITY;
    #pragma unroll
    for (int w = 0; w < 8; ++w) {
        float4 p0 = *(const float4*)&part[w][0];
        float4 p1 = *(const float4*)&part[w][4];
        float4 p2 = *(const float4*)&part[w][8];
        qg[0] += p0.x; qg[1] += p0.y; qg[2] += p0.z; qg[3] += p0.w;
        qg[4] += p1.x; qg[5] += p1.y; qg[6] += p1.z; qg[7] += p1.w;
        cnt += p2.x;
        kmax = fmaxf(kmax, p2.y);
        kmin = fminf(kmin, p2.z);
    }
    const float rdenom = 1.f / (cnt + 1e-5f);
    float qh[8];
    #pragma unroll
    for (int h = 0; h < 8; ++h) {
        float acc = 0.f;
        #pragma unroll
        for (int c = 0; c < 8; ++c) acc += (qg[c] * rdenom) * wq[h * 8 + c];
        qh[h] = acc;
    }

    // ---- stage-2: wave `wave` owns head h=wave; lanes span contiguous s ----
    {
        const float q = qh[wave];
        const float rowmax = (q >= 0.f) ? q * kmax : q * kmin;
        const int base = lane * 8;
        float4 k0 = *(const float4*)&kvs[base], k1 = *(const float4*)&kvs[base + 4];
        float4 v0 = *(const float4*)&vvs[base], v1 = *(const float4*)&vvs[base + 4];
        float4 m0 = *(const float4*)&mks[base], m1 = *(const float4*)&mks[base + 4];
        float kk[8] = {k0.x,k0.y,k0.z,k0.w,k1.x,k1.y,k1.z,k1.w};
        float vk[8] = {v0.x,v0.y,v0.z,v0.w,v1.x,v1.y,v1.z,v1.w};
        float mk[8] = {m0.x,m0.y,m0.z,m0.w,m1.x,m1.y,m1.z,m1.w};
        float sz = 0.f, sc = 0.f;
        #pragma unroll
        for (int j = 0; j < 8; ++j) {
            const float e = (mk[j] > 0.f) ? __expf(q * kk[j] - rowmax) : 0.f;
            sz += e;
            sc += e * vk[j];
        }
        #pragma unroll
        for (int d = 1; d < 64; d <<= 1) {
            sz += __shfl_xor(sz, d, 64);
            sc += __shfl_xor(sc, d, 64);
        }
        if (lane == 0) ctxs[wave] = (sz > 0.f) ? (sc / sz) : 0.f;
    }
    __syncthreads();   // barrier 2: ctxs visible

    float4 c0 = *(const float4*)&ctxs[0];
    float4 c1 = *(const float4*)&ctxs[4];
    float ctx[8] = {c0.x,c0.y,c0.z,c0.w,c1.x,c1.y,c1.z,c1.w};

    // ---- gate + output projection ----
    float o8[8];
    #pragma unroll
    for (int c = 0; c < 8; ++c) o8[c] = bo[c];
    if (valid) {
        #pragma unroll
        for (int h = 0; h < 8; ++h) {
            const float gate = 1.f / (1.f + __expf(-gh[h]));
            const float oh = gate * ctx[h];
            #pragma unroll
            for (int c = 0; c < 8; ++c) o8[c] += oh * wo[c * 8 + h];
        }
    }
    float* op = out + (s * R_RES + i) * C_CH;
    *(float4*)(op)     = make_float4(o8[0], o8[1], o8[2], o8[3]);
    *(float4*)(op + 4) = make_float4(o8[4], o8[5], o8[6], o8[7]);
}

extern "C" void kernel_launch(void* const* d_in, const int* in_sizes, int n_in,
                              void* d_out, int out_size, void* d_ws, size_t ws_size,
                              hipStream_t stream) {
    const float* m     = (const float*)d_in[0];
    const float* mmask = (const float*)d_in[1];
    const float* ln_w  = (const float*)d_in[2];
    const float* ln_b  = (const float*)d_in[3];
    const float* wq    = (const float*)d_in[4];
    const float* wk    = (const float*)d_in[5];
    const float* wv    = (const float*)d_in[6];
    const float* wg    = (const float*)d_in[7];
    const float* bg    = (const float*)d_in[8];
    const float* wo    = (const float*)d_in[9];
    const float* bo    = (const float*)d_in[10];
    float* out = (float*)d_out;

    msa_col_global_attn<<<dim3(R_RES), dim3(S_SEQ), 0, stream>>>(
        m, mmask, ln_w, ln_b, wq, wk, wv, wg, bg, wo, bo, out);
}